// Round 1
// baseline (121.629 us; speedup 1.0000x reference)
//
#include <hip/hip_runtime.h>
#include <hip/hip_bf16.h>
#include <math.h>

// DCNv1 fused, bf16-MFMA, round 14: software-pipeline dcn_mfma.
// r13 counters: MfmaUtil 15.7, VALUBusy 26, HBM 12% -> latency-serialized,
// not throughput-bound (r13's 4x line-transaction cut changed nothing).
// r14: double-buffer s_wA/s_col, issue chunk ch+1's corner gathers + weight
// DMA before finishing chunk ch, raw s_barrier + counted s_waitcnt vmcnt(5)
// (never 0 in-loop) so gather/DMA latency hides under FMA+MFMA of the
// previous chunk. One chunk = 2 light barriers, no full vmcnt drains.

constexpr int B  = 4;
constexpr int C  = 256;
constexpr int H  = 64;
constexpr int W  = 64;
constexpr int OC = 256;
constexpr int Ho = 64;
constexpr int Wo = 64;

constexpr int NT     = 64;   // positions per block (full wo row)
constexpr int CHUNKS = 72;   // 2304 / 32
constexpr int WROW   = 40;   // padded row (bf16): 80 B rows

constexpr size_t WA_ELTS  = (size_t)CHUNKS * OC * WROW;   // 737280 ushorts
constexpr size_t XB_ELTS  = (size_t)B * 8 * 4096 * 32;    // 4194304 ushorts
constexpr size_t OUT_ELTS = (size_t)B * OC * Ho * Wo;     // 4194304 floats

typedef __attribute__((ext_vector_type(8))) short bf16x8;
typedef __attribute__((ext_vector_type(4))) float f32x4;

__device__ __forceinline__ float bf_lo(unsigned u) {
    union { unsigned i; float f; } c; c.i = u << 16; return c.f;
}
__device__ __forceinline__ float bf_hi(unsigned u) {
    union { unsigned i; float f; } c; c.i = u & 0xffff0000u; return c.f;
}
__device__ __forceinline__ ushort fbf(float f) {
    __hip_bfloat16 h = __float2bfloat16(f); return *(ushort*)&h;
}

// ---- fused pre-pass: blocks 0..1023 transpose x, blocks 1024..1279 do w ----
__global__ __launch_bounds__(256)
void prep_all(const float* __restrict__ x, const float* __restrict__ wt,
              ushort* __restrict__ xb, ushort* __restrict__ wA)
{
    __shared__ ushort sx[128 * WROW];         // x path: [hw][40]
    __shared__ ushort sw[CHUNKS * WROW];      // w path: [ch][40]
    const int t = threadIdx.x;

    if (blockIdx.x < 1024) {
        // ---- x: fp32 NCHW -> bf16 [b][cb][hw][c32] ----
        const int blk = blockIdx.x;           // (b*8+cb)*32 + hwb
        const int hwb = blk & 31;
        const int cb  = (blk >> 5) & 7;
        const int b   = blk >> 8;
        const int hw0 = hwb << 7;
        const int lhw = t & 127, chalf = t >> 7;
        #pragma unroll
        for (int i = 0; i < 16; ++i) {
            const int c = i * 2 + chalf;      // 0..31
            sx[lhw * WROW + c] =
                fbf(x[(((size_t)(b * 256 + cb * 32 + c)) << 12) + hw0 + lhw]);
        }
        __syncthreads();
        const int whw = t >> 1, wh = t & 1;   // 4 uint4 per 64-B hw row
        const uint4 v0 = *(const uint4*)&sx[whw * WROW + wh * 16];
        const uint4 v1 = *(const uint4*)&sx[whw * WROW + wh * 16 + 8];
        uint4* dst = (uint4*)(xb + ((size_t)((b * 8 + cb) * 4096 + hw0) << 5));
        dst[whw * 4 + wh * 2 + 0] = v0;
        dst[whw * 4 + wh * 2 + 1] = v1;
    } else {
        // ---- w: fp32 [oc][c][tap] -> bf16 wA[ch][oc][40] ----
        const int oc = blockIdx.x - 1024;
        const int c  = t, chb = c >> 5, kk = c & 31;
        const float* wp = wt + ((size_t)oc * C + c) * 9;
        #pragma unroll
        for (int tap = 0; tap < 9; ++tap)
            sw[(tap * 8 + chb) * WROW + kk] = fbf(wp[tap]);
        if (c < CHUNKS) {
            #pragma unroll
            for (int j = 0; j < 8; ++j) sw[c * WROW + 32 + j] = 0;
        }
        __syncthreads();
        const uint4* sv = (const uint4*)sw;
        for (int i = c; i < CHUNKS * 5; i += 256) {
            const int row = i / 5, q = i % 5;
            ((uint4*)(wA + ((size_t)row * OC + oc) * WROW))[q] = sv[i];
        }
    }
}

struct GathRegs { uint4 c00, c01, c10, c11; float4 mw; };

// ---------------- main fused kernel ----------------------------------------
__global__ __launch_bounds__(512, 4)
void dcn_mfma(const ushort* __restrict__ xb, const float* __restrict__ off,
              const ushort* __restrict__ wA_g, float* __restrict__ po)
{
    // double-buffered staging (total LDS 65,024 B -> still 2 blocks/CU)
    __shared__ __align__(16) ushort s_wA[2][OC * WROW];   // 2 x 20480 B
    __shared__ __align__(16) ushort s_col[2][NT * WROW];  // 2 x  5120 B
    __shared__ __align__(16) float4 s_mw[9 * NT];         //  9216 B
    __shared__ __align__(8)  int2   s_midx[9 * NT];       //  4608 B

    // XCD swizzle: same b / ho-half (both khalves of a (b,ho)) per XCD.
    const int xcd = blockIdx.x & 7;
    const int ii  = blockIdx.x >> 3;            // 0..63
    const int b   = xcd & 3;
    const int khalf = ii & 1;
    const int ho  = ((xcd >> 2) << 5) + (ii >> 1);
    const int ch0 = khalf * 36;
    float* outp = po + (size_t)khalf * OUT_ELTS;
    const int tid = threadIdx.x;

    // ---- Phase A: bilinear meta per (tap, n); zero-fold padding into wts ----
    for (int s = tid; s < 9 * NT; s += 512) {
        const int n   = s & 63;
        const int tap = s >> 6;
        const float dy = off[((size_t)(b * 18 + 2 * tap)     * Ho + ho) * Wo + n];
        const float dx = off[((size_t)(b * 18 + 2 * tap + 1) * Ho + ho) * Wo + n];
        const float ph = (float)(ho - 1 + tap / 3) + dy;
        const float pw = (float)(n  - 1 + tap % 3) + dx;
        const float h0f = floorf(ph), w0f = floorf(pw);
        const int h0 = (int)h0f, w0 = (int)w0f;
        const float lh = ph - h0f, lw = pw - w0f;
        const int wb = min(max(w0, 0), W - 2);      // pair base stays in-plane
        const int ht = min(max(h0, 0), H - 1);
        const int hb = min(max(h0 + 1, 0), H - 1);
        const float s0 = (wb == w0) ? (1.f - lw) : ((wb == w0 + 1) ? lw : 0.f);
        const float s1 = (wb + 1 == w0 + 1) ? lw : ((wb + 1 == w0) ? (1.f - lw) : 0.f);
        const float wtp = (h0 >= 0 && h0 < H)         ? (1.f - lh) : 0.f;
        const float wbt = (h0 + 1 >= 0 && h0 + 1 < H) ? lh         : 0.f;
        s_midx[s] = make_int2(ht * W + wb, hb * W + wb);
        s_mw[s]   = make_float4(wtp * s0, wtp * s1, wbt * s0, wbt * s1);
    }

    const int lane = tid & 63;
    const int wv   = tid >> 6;        // 0..7
    const int ocb  = wv >> 1;         // oc block of 64
    const int phh  = wv & 1;          // pos half of 32
    const int kq   = lane >> 4;
    const int mr   = lane & 15;
    const bool is_w = (tid < 256);

    // sampling lane map: adjacent lanes take the 4 quarters of one 64-B row.
    const int sm_tid = tid - 256;     // 0..255 valid when tid >= 256
    const int sn  = sm_tid >> 2;      // position 0..63
    const int sgg = sm_tid & 3;       // channel octet 0..3
    const ushort* xb_sg = xb + ((size_t)b << 20) + (sgg << 3);

    f32x4 acc[4][2];
    #pragma unroll
    for (int mt = 0; mt < 4; ++mt)
        #pragma unroll
        for (int nt = 0; nt < 2; ++nt)
            acc[mt][nt] = (f32x4){0.f, 0.f, 0.f, 0.f};

    // ---- helpers (inline, buf always a literal at call site) ----
    auto dmaw = [&](int ch, int buf) {
        #pragma unroll
        for (int i = 0; i < 5; ++i) {
            const int seg = wv * 5 + i;            // wave-uniform
            __builtin_amdgcn_global_load_lds(
                (const __attribute__((address_space(1))) void*)
                    (wA_g + (size_t)ch * OC * WROW + seg * 512 + lane * 8),
                (__attribute__((address_space(3))) void*)&s_wA[buf][seg * 512],
                16, 0, 0);
        }
    };
    auto issueg = [&](int ch, GathRegs& g) {       // issue 4 corner gathers
        const int tap = ch >> 3;
        const int cb  = ch & 7;
        const int2 mi = s_midx[tap * NT + sn];     // broadcast (4 lanes)
        g.mw = s_mw[tap * NT + sn];
        const ushort* xp = xb_sg + ((size_t)cb << 17);
        g.c00 = *(const uint4*)(xp + ((size_t)mi.x << 5));
        g.c01 = *(const uint4*)(xp + (((size_t)mi.x + 1) << 5));
        g.c10 = *(const uint4*)(xp + ((size_t)mi.y << 5));
        g.c11 = *(const uint4*)(xp + (((size_t)mi.y + 1) << 5));
    };
    auto sampfma = [&](const GathRegs& g, int buf) {
        union { ushort pk[8]; uint4 v; } u;
        const unsigned a00[4] = {g.c00.x, g.c00.y, g.c00.z, g.c00.w};
        const unsigned a01[4] = {g.c01.x, g.c01.y, g.c01.z, g.c01.w};
        const unsigned a10[4] = {g.c10.x, g.c10.y, g.c10.z, g.c10.w};
        const unsigned a11[4] = {g.c11.x, g.c11.y, g.c11.z, g.c11.w};
        #pragma unroll
        for (int j = 0; j < 4; ++j) {
            const float vlo = g.mw.x * bf_lo(a00[j]) + g.mw.y * bf_lo(a01[j])
                            + g.mw.z * bf_lo(a10[j]) + g.mw.w * bf_lo(a11[j]);
            const float vhi = g.mw.x * bf_hi(a00[j]) + g.mw.y * bf_hi(a01[j])
                            + g.mw.z * bf_hi(a10[j]) + g.mw.w * bf_hi(a11[j]);
            u.pk[2 * j]     = fbf(vlo);
            u.pk[2 * j + 1] = fbf(vhi);
        }
        *(uint4*)&s_col[buf][sn * WROW + sgg * 8] = u.v;
    };
    auto mfmaph = [&](int buf) {
        const bf16x8 bfr0 = *(const bf16x8*)&s_col[buf][((phh * 2 + 0) * 16 + mr) * WROW + kq * 8];
        const bf16x8 bfr1 = *(const bf16x8*)&s_col[buf][((phh * 2 + 1) * 16 + mr) * WROW + kq * 8];
        #pragma unroll
        for (int mt = 0; mt < 4; ++mt) {
            const bf16x8 afr = *(const bf16x8*)&s_wA[buf][(ocb * 64 + mt * 16 + mr) * WROW + kq * 8];
            acc[mt][0] = __builtin_amdgcn_mfma_f32_16x16x32_bf16(afr, bfr0, acc[mt][0], 0, 0, 0);
            acc[mt][1] = __builtin_amdgcn_mfma_f32_16x16x32_bf16(afr, bfr1, acc[mt][1], 0, 0, 0);
        }
    };

    __syncthreads();                  // meta visible (one full drain, outside loop)

    GathRegs gA, gB;
    // ---- prologue: prefetch chunk ch0 ----
    if (is_w) dmaw(ch0, 0);
    else      issueg(ch0, gA);

    // ---- pipelined K loop: 18 x 2 chunks, named reg-set rotation ----
    #pragma unroll 1
    for (int it = 0; it < 18; ++it) {
        const int ch = ch0 + 2 * it;

        // phase 0: consume buf0/gA, prefetch ch+1 into buf1/gB
        if (is_w) {
            dmaw(ch + 1, 1);                        // always valid (2*it+1 <= 35)
            asm volatile("s_waitcnt vmcnt(5)" ::: "memory");  // ch's 5 DMAs done
        } else {
            issueg(ch + 1, gB);                     // loads in flight across MFMA
            sampfma(gA, 0);                         // auto-waits gA's gathers
            asm volatile("s_waitcnt lgkmcnt(0)" ::: "memory");
        }
        __builtin_amdgcn_s_barrier();
        __builtin_amdgcn_sched_barrier(0);
        mfmaph(0);
        __builtin_amdgcn_sched_barrier(0);
        __builtin_amdgcn_s_barrier();               // buf0 readers done

        // phase 1: consume buf1/gB, prefetch ch+2 into buf0/gA
        if (is_w) {
            if (it < 17) {
                dmaw(ch + 2, 0);
                asm volatile("s_waitcnt vmcnt(5)" ::: "memory");
            } else {
                asm volatile("s_waitcnt vmcnt(0)" ::: "memory");
            }
        } else {
            if (it < 17) issueg(ch + 2, gA);
            sampfma(gB, 1);
            asm volatile("s_waitcnt lgkmcnt(0)" ::: "memory");
        }
        __builtin_amdgcn_s_barrier();
        __builtin_amdgcn_sched_barrier(0);
        mfmaph(1);
        __builtin_amdgcn_sched_barrier(0);
        __builtin_amdgcn_s_barrier();               // buf1 readers done
    }

    // ---- epilogue: C/D layout col = lane&15 (pos), row = kq*4 + r (oc) ----
    #pragma unroll
    for (int mt = 0; mt < 4; ++mt)
        #pragma unroll
        for (int nt = 0; nt < 2; ++nt)
            #pragma unroll
            for (int r = 0; r < 4; ++r) {
                const int oc = ocb * 64 + mt * 16 + kq * 4 + r;
                const int wo = (phh * 2 + nt) * 16 + mr;
                outp[((size_t)(b * OC + oc) * Ho + ho) * Wo + wo] = acc[mt][nt][r];
            }
}

// ---- reduce: out = p0 + p1 (float4) ---------------------------------------
__global__ __launch_bounds__(256)
void reduce2(const float4* __restrict__ p0, const float4* __restrict__ p1,
             float4* __restrict__ out)
{
    const int i = blockIdx.x * 256 + threadIdx.x;   // over OUT_ELTS/4
    const float4 a = p0[i], b = p1[i];
    out[i] = make_float4(a.x + b.x, a.y + b.y, a.z + b.z, a.w + b.w);
}

extern "C" void kernel_launch(void* const* d_in, const int* in_sizes, int n_in,
                              void* d_out, int out_size, void* d_ws, size_t ws_size,
                              hipStream_t stream)
{
    const float* x   = (const float*)d_in[0];
    const float* off = (const float*)d_in[1];
    const float* wt  = (const float*)d_in[2];
    float* out = (float*)d_out;

    ushort* wA = (ushort*)d_ws;                 // 1.47 MB
    ushort* xb = wA + WA_ELTS;                  // 8.39 MB
    float*  po = (float*)(xb + XB_ELTS);        // 2 x 16.78 MB partials

    prep_all<<<1280, 256, 0, stream>>>(x, wt, xb, wA);
    dcn_mfma<<<512, 512, 0, stream>>>(xb, off, wA, po);
    reduce2<<<(int)(OUT_ELTS / 4 / 256), 256, 0, stream>>>(
        (const float4*)po, (const float4*)(po + OUT_ELTS), (float4*)out);
}

// Round 2
// 113.599 us; speedup vs baseline: 1.0707x; 1.0707x over previous
//
#include <hip/hip_runtime.h>
#include <hip/hip_bf16.h>
#include <math.h>

// DCNv1 fused, bf16-MFMA, round 15: homogeneous waves + 2-chunk phases.
// r14 post-mortem: depth-1 pipeline + counted vmcnt was NEUTRAL (46.5->48.8us)
// -> bottleneck is NOT memory latency; it is barrier-rate x heterogeneous wave
// roles (~1630 CU-cyc/chunk for ~400 cyc of work).
// r15 changes:
//  * ALL 8 waves sample (512 tasks = 2 chunks/phase) - balanced barrier arrival
//  * weight path: no LDS staging at all; prep_all writes weights in MFMA
//    fragment order (1KB per (chunk, 16-oc-group)); each wave loads its own
//    A-frags as coalesced dwordx4 (wave map 8 waves x 32oc x 64pos -> zero
//    duplicate weight lines). All loads register-destined -> compiler handles
//    all waitcnts fine-grained.
//  * ONE barrier per 2-chunk phase (4x fewer than r13): double-buffered s_col
//    makes the single mid-phase barrier sufficient.

constexpr int B  = 4;
constexpr int C  = 256;
constexpr int H  = 64;
constexpr int W  = 64;
constexpr int OC = 256;
constexpr int Ho = 64;
constexpr int Wo = 64;

constexpr int NT     = 64;   // positions per block (full wo row)
constexpr int CHUNKS = 72;   // 2304 / 32
constexpr int WROW   = 40;   // padded s_col row (bf16): 80 B rows

constexpr size_t WB_ELTS  = (size_t)CHUNKS * 16 * 512;    // 589824 ushorts (frag-order weights)
constexpr size_t XB_ELTS  = (size_t)B * 8 * 4096 * 32;    // 4194304 ushorts
constexpr size_t OUT_ELTS = (size_t)B * OC * Ho * Wo;     // 4194304 floats

typedef __attribute__((ext_vector_type(8))) short bf16x8;
typedef __attribute__((ext_vector_type(4))) float f32x4;

__device__ __forceinline__ float bf_lo(unsigned u) {
    union { unsigned i; float f; } c; c.i = u << 16; return c.f;
}
__device__ __forceinline__ float bf_hi(unsigned u) {
    union { unsigned i; float f; } c; c.i = u & 0xffff0000u; return c.f;
}
__device__ __forceinline__ ushort fbf(float f) {
    __hip_bfloat16 h = __float2bfloat16(f); return *(ushort*)&h;
}

// ---- fused pre-pass: blocks 0..1023 transpose x, blocks 1024..1279 do w ----
__global__ __launch_bounds__(256)
void prep_all(const float* __restrict__ x, const float* __restrict__ wt,
              ushort* __restrict__ xb, ushort* __restrict__ wB)
{
    __shared__ ushort sx[128 * WROW];         // x path: [hw][40]
    __shared__ ushort sw[CHUNKS * WROW];      // w path: [ch][40]
    const int t = threadIdx.x;

    if (blockIdx.x < 1024) {
        // ---- x: fp32 NCHW -> bf16 [b][cb][hw][c32] ----
        const int blk = blockIdx.x;           // (b*8+cb)*32 + hwb
        const int hwb = blk & 31;
        const int cb  = (blk >> 5) & 7;
        const int b   = blk >> 8;
        const int hw0 = hwb << 7;
        const int lhw = t & 127, chalf = t >> 7;
        #pragma unroll
        for (int i = 0; i < 16; ++i) {
            const int c = i * 2 + chalf;      // 0..31
            sx[lhw * WROW + c] =
                fbf(x[(((size_t)(b * 256 + cb * 32 + c)) << 12) + hw0 + lhw]);
        }
        __syncthreads();
        const int whw = t >> 1, wh = t & 1;   // 4 uint4 per 64-B hw row
        const uint4 v0 = *(const uint4*)&sx[whw * WROW + wh * 16];
        const uint4 v1 = *(const uint4*)&sx[whw * WROW + wh * 16 + 8];
        uint4* dst = (uint4*)(xb + ((size_t)((b * 8 + cb) * 4096 + hw0) << 5));
        dst[whw * 4 + wh * 2 + 0] = v0;
        dst[whw * 4 + wh * 2 + 1] = v1;
    } else {
        // ---- w: fp32 [oc][c][tap] -> bf16 fragment-order wB ----
        // wB piece (ch, og=oc>>4): 1024 B = 64 lanes x 16 B; lane l = kq*16+mr
        // holds {oc = og*16+mr, k = kq*8..kq*8+7 of chunk ch}.
        const int oc = blockIdx.x - 1024;
        const int c  = t, chb = c >> 5, kk = c & 31;
        const float* wp = wt + ((size_t)oc * C + c) * 9;
        #pragma unroll
        for (int tap = 0; tap < 9; ++tap)
            sw[(tap * 8 + chb) * WROW + kk] = fbf(wp[tap]);
        __syncthreads();
        const int og = oc >> 4, mr = oc & 15;
        for (int i = t; i < CHUNKS * 4; i += 256) {
            const int ch = i >> 2, kq = i & 3;
            *(uint4*)(wB + ((size_t)ch * 16 + og) * 512 + (kq * 16 + mr) * 8) =
                *(const uint4*)&sw[ch * WROW + kq * 8];
        }
    }
}

struct GathRegs { uint4 c00, c01, c10, c11; float4 mw; };

// ---------------- main fused kernel ----------------------------------------
__global__ __launch_bounds__(512, 4)
void dcn_mfma(const ushort* __restrict__ xb, const float* __restrict__ off,
              const ushort* __restrict__ wB, float* __restrict__ po)
{
    // double-buffered col tiles: [buf][kc][pos*40 + k8*8]
    __shared__ __align__(16) ushort s_col[2][2][NT * WROW];  // 20480 B
    __shared__ __align__(16) float4 s_mw[9 * NT];            //  9216 B
    __shared__ __align__(8)  int2   s_midx[9 * NT];          //  4608 B

    // XCD swizzle: same b per XCD for xb L2 locality.
    const int xcd = blockIdx.x & 7;
    const int ii  = blockIdx.x >> 3;            // 0..63
    const int b   = xcd & 3;
    const int khalf = ii & 1;
    const int ho  = ((xcd >> 2) << 5) + (ii >> 1);
    const int ch0 = khalf * 36;
    float* outp = po + (size_t)khalf * OUT_ELTS;
    const int tid = threadIdx.x;

    // ---- Phase A: bilinear meta per (tap, n); zero-fold padding into wts ----
    for (int s = tid; s < 9 * NT; s += 512) {
        const int n   = s & 63;
        const int tap = s >> 6;
        const float dy = off[((size_t)(b * 18 + 2 * tap)     * Ho + ho) * Wo + n];
        const float dx = off[((size_t)(b * 18 + 2 * tap + 1) * Ho + ho) * Wo + n];
        const float ph = (float)(ho - 1 + tap / 3) + dy;
        const float pw = (float)(n  - 1 + tap % 3) + dx;
        const float h0f = floorf(ph), w0f = floorf(pw);
        const int h0 = (int)h0f, w0 = (int)w0f;
        const float lh = ph - h0f, lw = pw - w0f;
        const int wb = min(max(w0, 0), W - 2);      // pair base stays in-plane
        const int ht = min(max(h0, 0), H - 1);
        const int hb = min(max(h0 + 1, 0), H - 1);
        const float s0 = (wb == w0) ? (1.f - lw) : ((wb == w0 + 1) ? lw : 0.f);
        const float s1 = (wb + 1 == w0 + 1) ? lw : ((wb + 1 == w0) ? (1.f - lw) : 0.f);
        const float wtp = (h0 >= 0 && h0 < H)         ? (1.f - lh) : 0.f;
        const float wbt = (h0 + 1 >= 0 && h0 + 1 < H) ? lh         : 0.f;
        s_midx[s] = make_int2(ht * W + wb, hb * W + wb);
        s_mw[s]   = make_float4(wtp * s0, wtp * s1, wbt * s0, wbt * s1);
    }

    const int lane = tid & 63;
    const int wv   = tid >> 6;        // 0..7 : oc-group of 32
    const int kq   = lane >> 4;
    const int mr   = lane & 15;

    // sampling task map: every thread samples one (kc, sn, sgg) per phase.
    const int kc_t = tid >> 8;        // which of the phase's 2 chunks
    const int st   = tid & 255;
    const int sn   = st >> 2;         // position 0..63
    const int sgg  = st & 3;          // channel octet 0..3 (adjacent lanes
                                      //  take 4 quarters of one 64-B row)
    const ushort* xb_sg = xb + ((size_t)b << 20) + (sgg << 3);

    f32x4 acc[2][4];                  // [mt 16-oc][nt 16-pos]
    #pragma unroll
    for (int mt = 0; mt < 2; ++mt)
        #pragma unroll
        for (int nt = 0; nt < 4; ++nt)
            acc[mt][nt] = (f32x4){0.f, 0.f, 0.f, 0.f};

    auto issueg = [&](int p, GathRegs& g) {        // issue 4 corner gathers
        const int ch  = ch0 + 2 * p + kc_t;
        const int tap = ch >> 3;
        const int cb  = ch & 7;
        const int2 mi = s_midx[tap * NT + sn];     // broadcast (4 lanes)
        g.mw = s_mw[tap * NT + sn];
        const ushort* xp = xb_sg + ((size_t)cb << 17);
        g.c00 = *(const uint4*)(xp + ((size_t)mi.x << 5));
        g.c01 = *(const uint4*)(xp + (((size_t)mi.x + 1) << 5));
        g.c10 = *(const uint4*)(xp + ((size_t)mi.y << 5));
        g.c11 = *(const uint4*)(xp + (((size_t)mi.y + 1) << 5));
    };
    auto sampfma = [&](const GathRegs& g, int buf) {
        union { ushort pk[8]; uint4 v; } u;
        const unsigned a00[4] = {g.c00.x, g.c00.y, g.c00.z, g.c00.w};
        const unsigned a01[4] = {g.c01.x, g.c01.y, g.c01.z, g.c01.w};
        const unsigned a10[4] = {g.c10.x, g.c10.y, g.c10.z, g.c10.w};
        const unsigned a11[4] = {g.c11.x, g.c11.y, g.c11.z, g.c11.w};
        #pragma unroll
        for (int j = 0; j < 4; ++j) {
            const float vlo = g.mw.x * bf_lo(a00[j]) + g.mw.y * bf_lo(a01[j])
                            + g.mw.z * bf_lo(a10[j]) + g.mw.w * bf_lo(a11[j]);
            const float vhi = g.mw.x * bf_hi(a00[j]) + g.mw.y * bf_hi(a01[j])
                            + g.mw.z * bf_hi(a10[j]) + g.mw.w * bf_hi(a11[j]);
            u.pk[2 * j]     = fbf(vlo);
            u.pk[2 * j + 1] = fbf(vhi);
        }
        *(uint4*)&s_col[buf][kc_t][sn * WROW + sgg * 8] = u.v;
    };
    // one phase = sample 2 chunks -> barrier -> 16 MFMAs (K=64)
    auto phase = [&](int p, const GathRegs& gcur, int buf) {
        sampfma(gcur, buf);
        // A-frags for this phase: coalesced, issued pre-barrier so L2 latency
        // hides under the barrier + bfr reads.
        bf16x8 wf[2][2];
        const int chb = ch0 + 2 * p;
        #pragma unroll
        for (int kc = 0; kc < 2; ++kc)
            #pragma unroll
            for (int mt = 0; mt < 2; ++mt)
                wf[kc][mt] = *(const bf16x8*)
                    (wB + ((size_t)(chb + kc) * 16 + wv * 2 + mt) * 512 + lane * 8);
        asm volatile("s_waitcnt lgkmcnt(0)" ::: "memory");  // ds_write visible
        __builtin_amdgcn_s_barrier();
        __builtin_amdgcn_sched_barrier(0);
        __builtin_amdgcn_s_setprio(1);
        #pragma unroll
        for (int kc = 0; kc < 2; ++kc)
            #pragma unroll
            for (int nt = 0; nt < 4; ++nt) {
                const bf16x8 bfr = *(const bf16x8*)
                    &s_col[buf][kc][(nt * 16 + mr) * WROW + kq * 8];
                #pragma unroll
                for (int mt = 0; mt < 2; ++mt)
                    acc[mt][nt] = __builtin_amdgcn_mfma_f32_16x16x32_bf16(
                        wf[kc][mt], bfr, acc[mt][nt], 0, 0, 0);
            }
        __builtin_amdgcn_s_setprio(0);
    };

    __syncthreads();                  // meta visible (only full drain)

    GathRegs gA, gB;
    issueg(0, gA);                    // prologue prefetch

    #pragma unroll 1
    for (int it = 0; it < 9; ++it) {  // 18 phases, x2 named reg rotation
        issueg(2 * it + 1, gB);       // 2it+1 <= 17 always valid
        phase(2 * it, gA, 0);
        if (it < 8) issueg(2 * it + 2, gA);
        phase(2 * it + 1, gB, 1);
    }

    // ---- epilogue: C/D layout col = lane&15 (pos), row = kq*4 + r (oc) ----
    #pragma unroll
    for (int mt = 0; mt < 2; ++mt)
        #pragma unroll
        for (int nt = 0; nt < 4; ++nt)
            #pragma unroll
            for (int r = 0; r < 4; ++r) {
                const int oc = wv * 32 + mt * 16 + kq * 4 + r;
                const int wo = nt * 16 + mr;
                outp[((size_t)(b * OC + oc) * Ho + ho) * Wo + wo] = acc[mt][nt][r];
            }
}

// ---- reduce: out = p0 + p1 (float4) ---------------------------------------
__global__ __launch_bounds__(256)
void reduce2(const float4* __restrict__ p0, const float4* __restrict__ p1,
             float4* __restrict__ out)
{
    const int i = blockIdx.x * 256 + threadIdx.x;   // over OUT_ELTS/4
    const float4 a = p0[i], b = p1[i];
    out[i] = make_float4(a.x + b.x, a.y + b.y, a.z + b.z, a.w + b.w);
}

extern "C" void kernel_launch(void* const* d_in, const int* in_sizes, int n_in,
                              void* d_out, int out_size, void* d_ws, size_t ws_size,
                              hipStream_t stream)
{
    const float* x   = (const float*)d_in[0];
    const float* off = (const float*)d_in[1];
    const float* wt  = (const float*)d_in[2];
    float* out = (float*)d_out;

    ushort* wB = (ushort*)d_ws;                 // 1.18 MB
    ushort* xb = wB + WB_ELTS;                  // 8.39 MB
    float*  po = (float*)(xb + XB_ELTS);        // 2 x 16.78 MB partials

    prep_all<<<1280, 256, 0, stream>>>(x, wt, xb, wB);
    dcn_mfma<<<512, 512, 0, stream>>>(xb, off, wB, po);
    reduce2<<<(int)(OUT_ELTS / 4 / 256), 256, 0, stream>>>(
        (const float4*)po, (const float4*)(po + OUT_ELTS), (float4*)out);
}